// Round 7
// baseline (654.757 us; speedup 1.0000x reference)
//
#include <hip/hip_runtime.h>
#include <hip/hip_bf16.h>
#include <math.h>

// Problem constants
#define TT   4096     // T
#define BB   16       // B
#define NTOK 65536    // B*T
#define CIN  512      // IN_FEATS
#define EF   256      // EMBED_FEATS
#define NE   1024     // NUM_EMBED

typedef __attribute__((ext_vector_type(8))) short bf16x8;
typedef __attribute__((ext_vector_type(4))) float f32x4;

static __device__ __forceinline__ unsigned short f2bf(float f) {
  unsigned int u = __float_as_uint(f);
  u += 0x7fffu + ((u >> 16) & 1u);          // RNE
  return (unsigned short)(u >> 16);
}

// async global->LDS, 16B per lane; LDS dest is wave-uniform base + lane*16
#define GLL(gsrc, ldst) \
  __builtin_amdgcn_global_load_lds((const __attribute__((address_space(1))) void*)(gsrc), \
                                   (__attribute__((address_space(3))) void*)(ldst), 16, 0, 0)

// ---------------------------------------------------------------------------
// K0: W -> bf16 (f4 loads); E -> bf16*(-2) + fused e_norm. 384 blocks.
// ---------------------------------------------------------------------------
__global__ __launch_bounds__(256) void k_prep(const float* __restrict__ Wf,
                                              const float* __restrict__ Ef,
                                              unsigned short* __restrict__ Wbf,
                                              unsigned short* __restrict__ Ebf,
                                              float* __restrict__ e_norm) {
  int bid = blockIdx.x;
  int tid = threadIdx.x;
  if (bid < 128) {                      // W: 32768 float4s
    int i = bid * 256 + tid;
    float4 v = ((const float4*)Wf)[i];
    ushort4 o = {f2bf(v.x), f2bf(v.y), f2bf(v.z), f2bf(v.w)};
    ((ushort4*)Wbf)[i] = o;
  } else {                              // E: 65536 float4s; wave w -> code eb*4+w
    int eb = bid - 128;
    int i = eb * 256 + tid;
    float4 v = ((const float4*)Ef)[i];
    float s = v.x * v.x + v.y * v.y + v.z * v.z + v.w * v.w;
    ushort4 o = {f2bf(-2.f * v.x), f2bf(-2.f * v.y), f2bf(-2.f * v.z), f2bf(-2.f * v.w)};
    ((ushort4*)Ebf)[i] = o;
    int w = tid >> 6, l = tid & 63;
    for (int off = 32; off; off >>= 1) s += __shfl_down(s, off);
    if (l == 0) e_norm[eb * 4 + w] = s;
  }
}

// ---------------------------------------------------------------------------
// K1: projection GEMM. 512 thr / 128 tokens / block, 512 blocks.
// LDS 80 KB (af32 32K @0 | as 16K @32K | bs 32K @48K; xs 64K aliased @0)
// -> 2 blocks/CU, 16 waves/CU; the two blocks' mem/MFMA phases overlap.
// A staged as raw f32 [64c][128t] via 16B GLL (full-BW HBM), transposed+
// converted through LDS (2-way banks, free). W via GLL. (512,2) -> 128 VGPR.
// Output: x_bf plain rows [tok][256] bf16 + sse += sum(x^2).
// ---------------------------------------------------------------------------
__global__ __launch_bounds__(512, 2) void k_gemm1(const float* __restrict__ in,
                                                  const unsigned short* __restrict__ Wbf,
                                                  const float* __restrict__ bias,
                                                  unsigned short* __restrict__ x_bf,
                                                  float* __restrict__ sse) {
  __shared__ unsigned short lds[40960];   // 80 KB
  float* af32 = (float*)lds;              // [64 c][128 t] f32   32 KB
  unsigned short* as_ = lds + 16384;      // [128 t][64 c] bf16  16 KB
  unsigned short* bs  = lds + 24576;      // [256 e][64 c] bf16  32 KB
  unsigned short* xs  = lds;              // [128 t][256 e] bf16 64 KB (epilogue)

  int tid = threadIdx.x;
  int w = tid >> 6, l = tid & 63;
  int l15 = l & 15, quad = l >> 4;
  int tq = w & 1, eq = w >> 1;            // MFMA wave tile: 64t x 64e
  int tok0 = blockIdx.x * 128;
  const float* src = in + (size_t)(tok0 >> 12) * CIN * TT + (tok0 & 4095);

  f32x4 acc[4][4];
#pragma unroll
  for (int a = 0; a < 4; ++a)
#pragma unroll
    for (int b = 0; b < 4; ++b) acc[a][b] = (f32x4){0.f, 0.f, 0.f, 0.f};

  int tconv = tid & 127, cg = tid >> 7;   // conversion map: token, c-group

  for (int ks = 0; ks < 8; ++ks) {
    int k0 = ks * 64;
    // W: 2048 16B chunks
#pragma unroll
    for (int i = 0; i < 4; ++i) {
      int g = i * 512 + tid;
      int row = g >> 3, pc = g & 7, lc = pc ^ (row & 7);
      GLL(Wbf + (size_t)row * CIN + k0 + lc * 8, bs + g * 8);
    }
    // A raw f32: 2048 16B chunks, [c][t] linear (row c = 32 chunks of 4 t)
#pragma unroll
    for (int i = 0; i < 4; ++i) {
      int g = i * 512 + tid;
      int c = g >> 5, col = g & 31;
      GLL(src + (size_t)(k0 + c) * TT + col * 4, ((unsigned short*)af32) + g * 8);
    }
    __syncthreads();
    // transpose+convert: thread owns token tconv, 16 c's (2-way banks, free)
    float vv[16];
#pragma unroll
    for (int i = 0; i < 16; ++i) vv[i] = af32[(cg * 16 + i) * 128 + tconv];
#pragma unroll
    for (int cc = 0; cc < 2; ++cc) {
      alignas(16) unsigned short tmp[8];
#pragma unroll
      for (int j = 0; j < 8; ++j) tmp[j] = f2bf(vv[cc * 8 + j]);
      int c8 = cg * 2 + cc;
      int pc = c8 ^ (tconv & 7);
      *(bf16x8*)(as_ + tconv * 64 + pc * 8) = *(const bf16x8*)tmp;
    }
    __syncthreads();
#pragma unroll
    for (int kstep = 0; kstep < 2; ++kstep) {
      int ck = kstep * 4 + quad;
      bf16x8 af[4], bfr[4];
#pragma unroll
      for (int msub = 0; msub < 4; ++msub) {
        int row = tq * 64 + msub * 16 + l15;
        int pa = ck ^ (row & 7);
        af[msub] = *(const bf16x8*)(as_ + row * 64 + pa * 8);
      }
#pragma unroll
      for (int nsub = 0; nsub < 4; ++nsub) {
        int row = eq * 64 + nsub * 16 + l15;
        int pb = ck ^ (row & 7);
        bfr[nsub] = *(const bf16x8*)(bs + row * 64 + pb * 8);
      }
#pragma unroll
      for (int msub = 0; msub < 4; ++msub)
#pragma unroll
        for (int nsub = 0; nsub < 4; ++nsub)
          acc[msub][nsub] = __builtin_amdgcn_mfma_f32_16x16x32_bf16(af[msub], bfr[nsub],
                                                                    acc[msub][nsub], 0, 0, 0);
    }
    __syncthreads();
  }

  // epilogue: bias, xsq, bf16 -> xs (swizzled), vector stores to x_bf
  float xsq = 0.f;
#pragma unroll
  for (int nsub = 0; nsub < 4; ++nsub) {
    int e = eq * 64 + nsub * 16 + l15;
    float bv = bias[e];
    int cx = e >> 3;
#pragma unroll
    for (int msub = 0; msub < 4; ++msub)
#pragma unroll
      for (int reg = 0; reg < 4; ++reg) {
        int m = tq * 64 + msub * 16 + quad * 4 + reg;
        float x = acc[msub][nsub][reg] + bv;
        xsq += x * x;
        int pcx = cx ^ (m & 31);
        xs[m * 256 + pcx * 8 + (e & 7)] = f2bf(x);
      }
  }
  __syncthreads();
#pragma unroll
  for (int i = 0; i < 4; ++i) {           // 2048 chunks: read swizzled, store plain
    int g = i * 512 + tid;
    int m = g >> 5, c = g & 31;
    int pcx = c ^ (m & 31);
    bf16x8 val = *(const bf16x8*)(xs + m * 256 + pcx * 8);
    *(bf16x8*)(x_bf + (size_t)(tok0 + m) * EF + c * 8) = val;
  }
  __shared__ float xred[8];
  for (int off = 32; off; off >>= 1) xsq += __shfl_down(xsq, off);
  if (l == 0) xred[w] = xsq;
  __syncthreads();
  if (tid == 0) {
    float t = 0.f;
#pragma unroll
    for (int i = 0; i < 8; ++i) t += xred[i];
    atomicAdd(sse, t);
  }
}

// ---------------------------------------------------------------------------
// K2: distances + argmin + fused gather/write. 512 thr / 128 tok / block,
// 512 blocks -> 2/CU, 16 waves/CU (the R6 fix: codebook split across wave
// pairs doubles resident waves). Wave (g3=w&3: 32-token strip, h=w>>2: 512
// codes). af[2][8] direct from global x_bf. LDS 64 KB = per-half double-
// buffered es: [half][parity][32 codes][256 k] (16 KB each). 16 chunks/half,
// one barrier/chunk, 32 MFMA/wave between. Argmin: shfl16 -> LDS merge of
// halves -> bi/hist/sse. Epilogue: z_q gather + transposed write (zq aliased
// at LDS+4KB).
// ---------------------------------------------------------------------------
__global__ __launch_bounds__(512, 2) void k_dist(const unsigned short* __restrict__ x_bf,
                                                 const unsigned short* __restrict__ Ebf,
                                                 const float* __restrict__ e_norm,
                                                 const float* __restrict__ embed,
                                                 float* __restrict__ out,
                                                 unsigned int* __restrict__ hist,
                                                 float* __restrict__ sse) {
  __shared__ unsigned short lds[32768];   // 64 KB
  float* redv  = (float*)lds;             // [2][128] (epilogue alias)
  int*   redi  = (int*)lds + 256;         // [2][128]
  int*   idxs  = (int*)lds + 512;         // [128]
  float* svred = (float*)lds + 640;       // [2]
  float* zq    = (float*)lds + 1024;      // [128][65] f32 = 33.3 KB @ byte 4096

  int tid = threadIdx.x;
  int w = tid >> 6, l = tid & 63;
  int l15 = l & 15, quad = l >> 4;
  int g3 = w & 3, h = w >> 2;
  int tok0 = blockIdx.x * 128;

  // A-fragments straight from global x_bf (each half-pair loads its own copy)
  bf16x8 af[2][8];
#pragma unroll
  for (int msub = 0; msub < 2; ++msub)
#pragma unroll
    for (int kst = 0; kst < 8; ++kst) {
      int row = tok0 + g3 * 32 + msub * 16 + l15;
      af[msub][kst] = *(const bf16x8*)(x_bf + (size_t)row * EF + (kst * 4 + quad) * 8);
    }

  // stage chunk 0 for both halves (2 x 16 KB = 2048 16B chunks)
#pragma unroll
  for (int i = 0; i < 4; ++i) {
    int g = i * 512 + tid;
    int half = g >> 10, gg = g & 1023;
    int row = gg >> 5, pcc = gg & 31, lc = pcc ^ (row & 31);
    GLL(Ebf + (size_t)(half * 512 + row) * EF + lc * 8,
        lds + half * 16384 + gg * 8);
  }
  float enn[2];
  enn[0] = e_norm[h * 512 + l15];
  enn[1] = e_norm[h * 512 + 16 + l15];
  __syncthreads();

  float best_v[2][4];
  int best_i[2][4];
#pragma unroll
  for (int a = 0; a < 2; ++a)
#pragma unroll
    for (int b = 0; b < 4; ++b) { best_v[a][b] = 3.0e38f; best_i[a][b] = 0; }

  for (int chunk = 0; chunk < 16; ++chunk) {
    int par = chunk & 1;
    if (chunk < 15) {                     // prefetch chunk+1 (both halves)
#pragma unroll
      for (int i = 0; i < 4; ++i) {
        int g = i * 512 + tid;
        int half = g >> 10, gg = g & 1023;
        int row = gg >> 5, pcc = gg & 31, lc = pcc ^ (row & 31);
        GLL(Ebf + (size_t)(half * 512 + (chunk + 1) * 32 + row) * EF + lc * 8,
            lds + half * 16384 + (par ^ 1) * 8192 + gg * 8);
      }
    }
    const unsigned short* eb = lds + h * 16384 + par * 8192;
    f32x4 dacc[2][2];
#pragma unroll
    for (int nsub = 0; nsub < 2; ++nsub) {
      float en = enn[nsub];
      dacc[0][nsub] = (f32x4){en, en, en, en};
      dacc[1][nsub] = (f32x4){en, en, en, en};
    }
    if (chunk < 15) {
      enn[0] = e_norm[h * 512 + (chunk + 1) * 32 + l15];
      enn[1] = e_norm[h * 512 + (chunk + 1) * 32 + 16 + l15];
    }
#pragma unroll
    for (int nsub = 0; nsub < 2; ++nsub) {
      int n = nsub * 16 + l15;
#pragma unroll
      for (int kst = 0; kst < 8; ++kst) {
        int pc = (kst * 4 + quad) ^ n;
        bf16x8 bfr = *(const bf16x8*)(eb + n * 256 + pc * 8);
        dacc[0][nsub] = __builtin_amdgcn_mfma_f32_16x16x32_bf16(af[0][kst], bfr,
                                                                dacc[0][nsub], 0, 0, 0);
        dacc[1][nsub] = __builtin_amdgcn_mfma_f32_16x16x32_bf16(af[1][kst], bfr,
                                                                dacc[1][nsub], 0, 0, 0);
      }
    }
#pragma unroll
    for (int msub = 0; msub < 2; ++msub)
#pragma unroll
      for (int nsub = 0; nsub < 2; ++nsub) {
        int code = h * 512 + chunk * 32 + nsub * 16 + l15;
#pragma unroll
        for (int reg = 0; reg < 4; ++reg) {
          float vv = dacc[msub][nsub][reg];
          if (vv < best_v[msub][reg]) { best_v[msub][reg] = vv; best_i[msub][reg] = code; }
        }
      }
    __syncthreads();
  }

  // per-wave argmin over the 16 l15 lanes -> LDS by half
#pragma unroll
  for (int msub = 0; msub < 2; ++msub)
#pragma unroll
    for (int reg = 0; reg < 4; ++reg) {
      float vv = best_v[msub][reg];
      int idx = best_i[msub][reg];
#pragma unroll
      for (int off = 8; off; off >>= 1) {
        float ov = __shfl_xor(vv, off, 16);
        int oi = __shfl_xor(idx, off, 16);
        if (ov < vv || (ov == vv && oi < idx)) { vv = ov; idx = oi; }
      }
      if (l15 == 0) {
        int tokloc = g3 * 32 + msub * 16 + quad * 4 + reg;
        redv[h * 128 + tokloc] = vv;
        redi[h * 128 + tokloc] = idx;
      }
    }
  __syncthreads();
  if (tid < 128) {                        // merge halves, final idx + hist + sse
    float v0 = redv[tid], v1 = redv[128 + tid];
    int i0 = redi[tid], i1 = redi[128 + tid];
    float vv; int idx;
    if (v1 < v0 || (v1 == v0 && i1 < i0)) { vv = v1; idx = i1; } else { vv = v0; idx = i0; }
    idxs[tid] = idx;
    atomicAdd(&hist[idx], 1u);
    for (int off = 32; off; off >>= 1) vv += __shfl_down(vv, off);
    if ((tid & 63) == 0) svred[tid >> 6] = vv;
  }
  __syncthreads();
  if (tid == 0) atomicAdd(sse, svred[0] + svred[1]);

  // fused gather + transposed z_q write: 4 passes of 64 e
  int b = tok0 >> 12, t0 = tok0 & 4095;
  for (int pass = 0; pass < 4; ++pass) {
    int e0 = pass * 64;
    if (pass) __syncthreads();
    for (int r = 0; r < 4; ++r) {
      int tl = r * 32 + (tid >> 4);
      const float4 vv = *(const float4*)(embed + (size_t)idxs[tl] * EF + e0 + (tid & 15) * 4);
      float* zr = zq + tl * 65 + (tid & 15) * 4;
      zr[0] = vv.x; zr[1] = vv.y; zr[2] = vv.z; zr[3] = vv.w;
    }
    __syncthreads();
    int e = tid >> 3, sub = tid & 7;
#pragma unroll
    for (int j = 0; j < 2; ++j) {
      int t4 = sub * 16 + j * 8;
      float4 va, vb;
      va.x = zq[(t4 + 0) * 65 + e]; va.y = zq[(t4 + 1) * 65 + e];
      va.z = zq[(t4 + 2) * 65 + e]; va.w = zq[(t4 + 3) * 65 + e];
      vb.x = zq[(t4 + 4) * 65 + e]; vb.y = zq[(t4 + 5) * 65 + e];
      vb.z = zq[(t4 + 6) * 65 + e]; vb.w = zq[(t4 + 7) * 65 + e];
      float* op = out + ((size_t)(b * EF + e0 + e) << 12) + t0 + t4;
      *(float4*)op = va;
      *(float4*)(op + 4) = vb;
    }
  }
}

// ---------------------------------------------------------------------------
// K3: finalize scalars
// ---------------------------------------------------------------------------
__global__ __launch_bounds__(256) void k_final(const unsigned int* __restrict__ hist,
                                               const float* __restrict__ sse,
                                               float* __restrict__ out) {
  __shared__ float red[4];
  int tid = threadIdx.x;
  float local = 0.f;
  for (int i = tid; i < NE; i += 256) {
    float p = (float)hist[i] * (1.0f / 65536.0f);
    local -= p * logf(p + 1e-10f);
  }
  for (int off = 32; off; off >>= 1) local += __shfl_down(local, off);
  if ((tid & 63) == 0) red[tid >> 6] = local;
  __syncthreads();
  if (tid == 0) {
    float lp = red[0] + red[1] + red[2] + red[3];
    out[16777216] = 1.25f * sse[0] / 16777216.0f;  // vq + 0.25*commitment
    out[16777233] = lp;
  }
  if (tid < 16) out[16777217 + tid] = 6.93147180559945f * 4096.0f;  // log(1024)*4096
}

// ---------------------------------------------------------------------------
extern "C" void kernel_launch(void* const* d_in, const int* in_sizes, int n_in,
                              void* d_out, int out_size, void* d_ws, size_t ws_size,
                              hipStream_t stream) {
  const float* inputs = (const float*)d_in[0];
  const float* proj_w = (const float*)d_in[1];
  const float* proj_b = (const float*)d_in[2];
  const float* embed = (const float*)d_in[3];
  float* out = (float*)d_out;
  char* ws = (char*)d_ws;

  // workspace layout
  unsigned short* x_bf = (unsigned short*)(ws);             // 33,554,432 B
  unsigned short* Wbf  = (unsigned short*)(ws + 33554432);  //    262,144 B
  unsigned short* Ebf  = (unsigned short*)(ws + 33816576);  //    524,288 B
  float* e_norm        = (float*)(ws + 34340864);           //      4,096 B
  unsigned int* hist   = (unsigned int*)(ws + 34344960);    //      4,096 B
  float* sse           = (float*)(ws + 34349056);           //          4 B
  if (ws_size < 34349060) return;

  hipMemsetAsync(ws + 34344960, 0, 4100, stream);  // hist + sse

  k_prep<<<384, 256, 0, stream>>>(proj_w, embed, Wbf, Ebf, e_norm);
  k_gemm1<<<512, 512, 0, stream>>>(inputs, Wbf, proj_b, x_bf, sse);
  k_dist<<<512, 512, 0, stream>>>(x_bf, Ebf, e_norm, embed, out, hist, sse);
  k_final<<<1, 256, 0, stream>>>(hist, sse, out);
}